// Round 3
// baseline (1415.265 us; speedup 1.0000x reference)
//
#include <hip/hip_runtime.h>

typedef unsigned short ushort_t;
typedef __attribute__((ext_vector_type(4))) float f32x4;
typedef __attribute__((ext_vector_type(8))) short s16x8;
typedef __attribute__((ext_vector_type(8))) unsigned short u16x8;

#define NB 16         // dialogues
#define NL 54         // utterances per dialogue
#define NT (NB*NL)    // 864
#define NNODE (3*NT)  // 2592
#define NEDGE 912     // hyperedges
#define MATSZ (512*512)
#define INV53 (1.0f/(53.0f + 1e-8f))
#define NBLK 16       // one block per dialogue

__device__ __forceinline__ ushort_t f2b(float f){
  union {unsigned int i; float f;} x; x.f = f;
  unsigned int r = (x.i + 0x7fffu + ((x.i>>16)&1u))>>16;
  return (ushort_t)r;
}

__device__ __forceinline__ void async_copy16(const ushort_t* g, ushort_t* l){
  __builtin_amdgcn_global_load_lds((const __attribute__((address_space(1))) void*)g,
                                   (__attribute__((address_space(3))) void*)l, 16, 0, 0);
}

struct MegaArgs {
  const float *A_in,*V_in,*L_in,*qmask,*spk,*fc1_b,*he_w,*ew_w,*attr1,*attr2,*hc_b,*m3_b;
  const float *fc1_W,*hc_W,*m3_W0,*m3_W1,*m3_Ws;
  const int *het;
  ushort_t *WT;
  float *X1,*OUT,*HS,*G,*EB,*Gsum,*Sp,*acc,*dout;
  unsigned int *bar;
};

// LDS layout: GEMM buffers alias the transpose tile (transpose only runs
// before the first barrier).  Everything else is persistent per-dialogue.
struct SMem {
  union {
    struct {
      ushort_t As[2][176*64];   // XOR-swizzled A slab (rows 0..175, 64 k)
      ushort_t Bs[2][128*64];   // XOR-swizzled B tile
    } g;
    float tile[64][65];         // weight-transpose staging
  } u;
  const float* rpA[176];        // per-row A-source descriptors
  const float* rpB[176];
  float rcA[176], rcB[176];
  float wm[162], wu[162];       // ew slices (modality / utterance order)
  float invde[57];
  int   hetl[57];
  unsigned char spks[54];
  float red[256];
};

// 16-block grid barrier: light contention (16 arrivals, 16 spinners).
__device__ __forceinline__ void gsync(unsigned int* bar, unsigned int tgt){
  __syncthreads();
  if (threadIdx.x==0){
    __hip_atomic_fetch_add(bar, 1u, __ATOMIC_RELEASE, __HIP_MEMORY_SCOPE_AGENT);
    while (__hip_atomic_load(bar, __ATOMIC_RELAXED, __HIP_MEMORY_SCOPE_AGENT) < tgt)
      __builtin_amdgcn_s_sleep(8);
    (void)__hip_atomic_load(bar, __ATOMIC_ACQUIRE, __HIP_MEMORY_SCOPE_AGENT);
  }
  __syncthreads();
}

// ---------------------------------------------------------------------------
// Weight transpose/convert: one 64x64 tile per job; slots 12..15 hold the
// combined (Wself - inv*W1) that eliminates the per-layer H1 GEMM.
// ---------------------------------------------------------------------------
__device__ void transpose_job(const MegaArgs& a, int job, char* smem){
  float (*tile)[65] = (float(*)[65])smem;
  int w = job>>6, t = job&63, bx = t>>3, by = t&7;
  const float* src = (w==0) ? a.fc1_W
                   : (w<4)  ? a.hc_W + (size_t)(w-1)*MATSZ
                   : (w<8)  ? a.m3_W0 + (size_t)(w-4)*MATSZ
                   : (w<12) ? a.m3_W1 + (size_t)(w-8)*MATSZ
                            : a.m3_Ws + (size_t)(w-12)*MATSZ;
  const float* src2 = (w>=12) ? a.m3_W1 + (size_t)(w-12)*MATSZ : nullptr;
  ushort_t* dst = a.WT + (size_t)w*MATSZ;
  int r0 = bx*64, c0 = by*64;
  __syncthreads();
  #pragma unroll
  for (int j=0;j<16;j++){
    int idx = j*256 + threadIdx.x;
    int r = idx>>6, c = idx&63;
    size_t off = (size_t)(r0+r)*512 + c0 + c;
    float v = src[off];
    if (w>=12) v -= INV53 * src2[off];
    tile[r][c] = v;
  }
  __syncthreads();
  #pragma unroll
  for (int j=0;j<16;j++){
    int idx = j*256 + threadIdx.x;
    int r = idx>>6, c = idx&63;
    dst[(size_t)(c0+r)*512 + r0 + c] = f2b(tile[c][r]);
  }
}

// ---------------------------------------------------------------------------
// Per-dialogue GEMM: out[162x512] = srcA(desc)[162x512] @ W[512x512] + bias.
// All 162 rows staged per 64-k step (As slab), B double-buffered via
// global_load_lds.  4 waves x (11 mfrag x 2 nfrag), nc-loop over 4x128 cols.
// ---------------------------------------------------------------------------
__device__ void dgemm(SMem* s, const ushort_t* W, const float* bias,
                      float* __restrict__ out, int d, bool relu)
{
  const int tid = threadIdx.x;
  const int wave = tid>>6, lane = tid&63;
  const int ml = lane&15, quad = lane>>4;
  const int lr = lane>>3, lchunk = lane&7;
  const int bswz = (lchunk ^ lr)*8;
  const int wcb = wave*32;

  for (int nc=0; nc<4; nc++){
    f32x4 acc[11][2];
    #pragma unroll
    for (int mf=0; mf<11; mf++){
      acc[mf][0] = (f32x4){0.f,0.f,0.f,0.f};
      acc[mf][1] = (f32x4){0.f,0.f,0.f,0.f};
    }
    f32x4 La[6],Lb[6],Lc[6],Ld[6];

    auto loadA = [&](int k0){
      #pragma unroll
      for (int it=0; it<6; it++){
        int c = it*256 + tid;
        if (c < 1408){
          int row = c>>3, k8 = c&7;
          const float* pA = s->rpA[row] + k0 + k8*8;
          const float* pB = s->rpB[row] + k0 + k8*8;
          La[it] = *(const f32x4*)pA;
          Lb[it] = *(const f32x4*)(pA+4);
          Lc[it] = *(const f32x4*)pB;
          Ld[it] = *(const f32x4*)(pB+4);
        }
      }
    };
    auto writeA = [&](int buf){
      #pragma unroll
      for (int it=0; it<6; it++){
        int c = it*256 + tid;
        if (c < 1408){
          int row = c>>3, k8 = c&7;
          float cA = s->rcA[row], cB = s->rcB[row];
          u16x8 v;
          #pragma unroll
          for (int j=0;j<4;j++){
            v[j]   = f2b(cA*La[it][j] + cB*Lc[it][j]);
            v[4+j] = f2b(cA*Lb[it][j] + cB*Ld[it][j]);
          }
          *(u16x8*)&s->u.g.As[buf][row*64 + ((k8 ^ (row&7))<<3)] = v;
        }
      }
    };
    auto stageB = [&](int buf, int k0){
      #pragma unroll
      for (int rep=0; rep<4; rep++){
        int bn0 = wave*32 + rep*8;
        const ushort_t* src = W + (size_t)(nc*128 + bn0 + lr)*512 + k0 + bswz;
        async_copy16(src, &s->u.g.Bs[buf][bn0*64]);
      }
    };

    loadA(0); stageB(0,0); writeA(0);
    int cur = 0;
    for (int ks=0; ks<8; ks++){
      __syncthreads();
      if (ks<7){ loadA((ks+1)*64); stageB(cur^1,(ks+1)*64); }
      #pragma unroll
      for (int kh=0; kh<2; kh++){
        const int k8r = kh*4 + quad;
        s16x8 b0, b1;
        {
          int bn = wcb + ml;
          b0 = *(const s16x8*)&s->u.g.Bs[cur][bn*64 + ((k8r ^ (bn&7))<<3)];
          bn = wcb + 16 + ml;
          b1 = *(const s16x8*)&s->u.g.Bs[cur][bn*64 + ((k8r ^ (bn&7))<<3)];
        }
        #pragma unroll
        for (int mf=0; mf<11; mf++){
          int ar = mf*16 + ml;
          s16x8 av = *(const s16x8*)&s->u.g.As[cur][ar*64 + ((k8r ^ (ar&7))<<3)];
          acc[mf][0] = __builtin_amdgcn_mfma_f32_16x16x32_bf16(av,b0,acc[mf][0],0,0,0);
          acc[mf][1] = __builtin_amdgcn_mfma_f32_16x16x32_bf16(av,b1,acc[mf][1],0,0,0);
        }
      }
      if (ks<7) writeA(cur^1);
      cur ^= 1;
    }
    // epilogue (C/D: col=lane&15, row=quad*4+reg)
    #pragma unroll
    for (int nf=0; nf<2; nf++){
      int col = nc*128 + wcb + nf*16 + ml;
      float bv = bias[col];
      #pragma unroll
      for (int mf=0; mf<11; mf++){
        int rb = mf*16 + quad*4;
        f32x4 v = acc[mf][nf];
        #pragma unroll
        for (int r=0;r<4;r++){
          int row = rb + r;
          if (row < 162){
            float x = v[r] + bv;
            if (relu) x = fmaxf(x, 0.f);
            out[(size_t)(d*162+row)*512 + col] = x;
          }
        }
      }
    }
    __syncthreads();
  }
}

// ---------------------------------------------------------------------------
// Hyperedge aggregation, whole dialogue: 256 thr x 2 cols.
// ---------------------------------------------------------------------------
__device__ void edge_stage(SMem* s, const MegaArgs& a, int d, const float* X){
  int c = threadIdx.x*2;
  float mx[3]={0.f,0.f,0.f}, my[3]={0.f,0.f,0.f};
  for (int i=0;i<54;i++){
    float ux=0.f, uy=0.f;
    #pragma unroll
    for (int m=0;m<3;m++){
      float2 x = *(const float2*)&X[(size_t)(d*162 + m*54 + i)*512 + c];
      float w  = s->wm[m*54+i];
      float wu = s->wu[i*3+m];
      mx[m] += w*x.x; my[m] += w*x.y;
      ux += wu*x.x; uy += wu*x.y;
    }
    float inv = s->invde[3+i];
    const float* at = s->hetl[3+i] ? a.attr1 : a.attr2;
    float2 o; o.x = ux*inv + at[c]; o.y = uy*inv + at[c+1];
    *(float2*)&a.EB[(size_t)(d*57+3+i)*512 + c] = o;
  }
  #pragma unroll
  for (int m=0;m<3;m++){
    float inv = s->invde[m];
    const float* at = s->hetl[m] ? a.attr1 : a.attr2;
    float2 o; o.x = mx[m]*inv + at[c]; o.y = my[m]*inv + at[c+1];
    *(float2*)&a.EB[(size_t)(d*57+m)*512 + c] = o;
  }
}

// ---------------------------------------------------------------------------
// Gsum of X1 (per group,speaker column sums), whole dialogue.
// ---------------------------------------------------------------------------
__device__ void gsum_stage(SMem* s, const MegaArgs& a, int d){
  int c = threadIdx.x*2;
  #pragma unroll
  for (int m=0;m<3;m++){
    float a0=0.f,b0=0.f,a1=0.f,b1=0.f;
    for (int i=0;i<54;i++){
      float2 x = *(const float2*)&a.X1[(size_t)(d*162+m*54+i)*512 + c];
      if (s->spks[i]){ a1+=x.x; b1+=x.y; } else { a0+=x.x; b0+=x.y; }
    }
    float2 o0; o0.x=a0; o0.y=b0;
    float2 o1; o1.x=a1; o1.y=b1;
    *(float2*)&a.Gsum[(size_t)((d*3+m)*2  )*512 + c] = o0;
    *(float2*)&a.Gsum[(size_t)((d*3+m)*2+1)*512 + c] = o1;
  }
}

// ---------------------------------------------------------------------------
// Sp[d] = (bf16)Gsum[d] @ [W0|W1]: 6x1024 via MFMA; wave w owns 256 cols.
// ---------------------------------------------------------------------------
__device__ void sp_stage(SMem* s, const MegaArgs& a, int d, int kk){
  const int tid = threadIdx.x;
  const int wave = tid>>6, lane = tid&63;
  const int ml = lane&15, quad = lane>>4;
  const ushort_t* Wb = a.WT + (size_t)((wave<2 ? 4 : 8)+kk)*MATSZ;
  const int colbase = (wave&1)*256;
  f32x4 accS[16];
  #pragma unroll
  for (int nf=0;nf<16;nf++) accS[nf] = (f32x4){0.f,0.f,0.f,0.f};
  for (int ks=0; ks<16; ks++){
    u16x8 af;
    if (ml < 6){
      const float* gr = a.Gsum + (size_t)(d*6+ml)*512 + ks*32 + quad*8;
      f32x4 xa = *(const f32x4*)gr, xb = *(const f32x4*)(gr+4);
      #pragma unroll
      for (int j=0;j<4;j++){ af[j]=f2b(xa[j]); af[4+j]=f2b(xb[j]); }
    } else {
      af = (u16x8){0,0,0,0,0,0,0,0};
    }
    #pragma unroll
    for (int nf=0; nf<16; nf++){
      const ushort_t* wp = Wb + (size_t)(colbase + nf*16 + ml)*512 + ks*32 + quad*8;
      s16x8 bf = *(const s16x8*)wp;
      accS[nf] = __builtin_amdgcn_mfma_f32_16x16x32_bf16((s16x8)af, bf, accS[nf],0,0,0);
    }
  }
  #pragma unroll
  for (int nf=0; nf<16; nf++){
    f32x4 v = accS[nf];
    #pragma unroll
    for (int r=0;r<4;r++){
      int row = quad*4 + r;
      if (row < 6)
        a.Sp[(size_t)(d*6+row)*1024 + wave*256 + nf*16 + ml] = v[r];
    }
  }
}

// ---------------------------------------------------------------------------
// Fused RGCN combine, whole dialogue: f=relu((S1+S0)*inv+hs); g+=f; Gsum out.
// ---------------------------------------------------------------------------
__device__ void sf_stage(SMem* s, const MegaArgs& a, int d, const float* gin, bool last){
  const int tid = threadIdx.x;
  int c = tid*2;
  float sumsq = 0.f;
  for (int m=0;m<3;m++){
    int g = d*3+m;
    const float* r0 = a.Sp + (size_t)(g*2)*1024;
    const float* r1 = a.Sp + (size_t)(g*2+1)*1024;
    float2 S1_0 = *(const float2*)&r0[512+c];
    float2 S1_1 = *(const float2*)&r1[512+c];
    float2 S0_0 = *(const float2*)&r1[c];
    float2 S0_1 = *(const float2*)&r0[c];
    float2 gs0; gs0.x=0.f; gs0.y=0.f;
    float2 gs1; gs1.x=0.f; gs1.y=0.f;
    for (int i=0;i<54;i++){
      size_t off = (size_t)(d*162+m*54+i)*512 + c;
      int sp = s->spks[i];
      float2 S1 = sp ? S1_1 : S1_0;
      float2 S0 = sp ? S0_1 : S0_0;
      float2 hs = *(const float2*)&a.HS[off];
      float2 gi = *(const float2*)&gin[off];
      float2 f;
      f.x = fmaxf((S1.x+S0.x)*INV53 + hs.x, 0.f);
      f.y = fmaxf((S1.y+S0.y)*INV53 + hs.y, 0.f);
      float2 gn; gn.x = gi.x+f.x; gn.y = gi.y+f.y;
      *(float2*)&a.G[off] = gn;
      if (sp){ gs1.x+=gn.x; gs1.y+=gn.y; } else { gs0.x+=gn.x; gs0.y+=gn.y; }
      if (last){
        sumsq += f.x*f.x + f.y*f.y;
        float2 ov = *(const float2*)&a.OUT[off];
        float2 o; o.x = ov.x+gn.x; o.y = ov.y+gn.y;
        *(float2*)&a.dout[off] = o;
      }
    }
    *(float2*)&a.Gsum[(size_t)(g*2  )*512 + c] = gs0;
    *(float2*)&a.Gsum[(size_t)(g*2+1)*512 + c] = gs1;
  }
  if (last){
    s->red[tid] = sumsq;
    __syncthreads();
    #pragma unroll
    for (int st=128; st>0; st>>=1){
      if (tid < st) s->red[tid] += s->red[tid+st];
      __syncthreads();
    }
    if (tid == 0) atomicAdd(a.acc, s->red[0]);
  }
}

// ---------------------------------------------------------------------------
// Persistent per-dialogue mega-kernel: 16 blocks, 2 grid barriers total.
// ---------------------------------------------------------------------------
__global__ __launch_bounds__(256,1) void mega(MegaArgs a)
{
  __shared__ SMem sm;
  const int bid = blockIdx.x;
  const int tid = threadIdx.x;
  const int d = bid;

  // cooperative weight transpose (1024 tile jobs over 16 blocks)
  for (int j=bid; j<1024; j+=NBLK) transpose_job(a, j, (char*)&sm);
  gsync(a.bar, NBLK);

  // per-dialogue constant caches
  if (tid<162){ sm.wm[tid]=a.ew_w[d*324+tid]; sm.wu[tid]=a.ew_w[d*324+162+tid]; }
  if (tid<57) sm.hetl[tid]=a.het[d*57+tid];
  if (tid<54) sm.spks[tid] = a.qmask[(tid*16+d)*2+1] > a.qmask[(tid*16+d)*2];
  __syncthreads();
  if (tid<54){
    float de = sm.wu[tid*3]+sm.wu[tid*3+1]+sm.wu[tid*3+2];
    sm.invde[3+tid] = 1.0f/(de+1e-8f);
  } else if (tid<57){
    int m = tid-54; float de=0.f;
    for (int i=0;i<54;i++) de += sm.wm[m*54+i];
    sm.invde[m] = 1.0f/(de+1e-8f);
  }
  // A-descriptors for feats (a/v/l + spk_emb)
  if (tid<176){
    int rc = tid>161?161:tid;
    int m=rc/54, i=rc-m*54, t=d*54+i;
    const float* base = ((m==0)?a.L_in:(m==1)?a.A_in:a.V_in) + (size_t)t*512;
    const float* pb = base; float cb = 0.f;
    if (m==0){
      int sp = a.qmask[(i*16+d)*2+1] > a.qmask[(i*16+d)*2];
      pb = a.spk + sp*512; cb = 1.f;
    }
    sm.rpA[tid]=base; sm.rpB[tid]=pb; sm.rcA[tid]=1.f; sm.rcB[tid]=cb;
  }
  __syncthreads();

  // x1 = feats @ fc1 + b
  dgemm(&sm, a.WT, a.fc1_b, a.X1, d, false);
  __syncthreads();
  gsum_stage(&sm, a, d);
  __syncthreads();

  // hypergraph conv x3
  const float* src = a.X1;
  for (int ll=0; ll<3; ll++){
    edge_stage(&sm, a, d, src);
    __syncthreads();
    if (tid<176){
      int rc = tid>161?161:tid;
      int m=rc/54, i=rc-m*54;
      int em=d*57+m, eu=d*57+3+i;
      float w1=a.he_w[em], w2=a.he_w[eu], inv=1.0f/(w1+w2+1e-8f);
      sm.rpA[tid]=a.EB+(size_t)em*512; sm.rpB[tid]=a.EB+(size_t)eu*512;
      sm.rcA[tid]=w1*inv; sm.rcB[tid]=w2*inv;
    }
    __syncthreads();
    dgemm(&sm, a.WT+(size_t)(1+ll)*MATSZ, a.hc_b+(size_t)ll*512, a.OUT, d, true);
    __syncthreads();
    src = a.OUT;
  }

  // RGCN denoise x4 (H1 folded into combined weight, slots 12..15)
  for (int kk=0; kk<4; kk++){
    const float* gin = kk ? a.G : a.X1;
    sp_stage(&sm, a, d, kk);
    if (tid<176){
      int rc = tid>161?161:tid;
      const float* p = gin + (size_t)(d*162+rc)*512;
      sm.rpA[tid]=p; sm.rpB[tid]=p; sm.rcA[tid]=1.f; sm.rcB[tid]=0.f;
    }
    __syncthreads();
    dgemm(&sm, a.WT+(size_t)(12+kk)*MATSZ, a.m3_b+(size_t)kk*512, a.HS, d, false);
    __syncthreads();
    sf_stage(&sm, a, d, gin, kk==3);
    __syncthreads();
  }

  // final denoise scalar
  gsync(a.bar, 2*NBLK);
  if (bid==0 && tid==0)
    a.dout[(size_t)NNODE*512] = atomicAdd(a.acc, 0.0f) * (1.0f/1327104.0f);
}

__global__ void init_kernel(unsigned int* bar, float* acc){
  if (threadIdx.x==0){ *bar = 0u; *acc = 0.0f; }
}

// ---------------------------------------------------------------------------
extern "C" void kernel_launch(void* const* d_in, const int* in_sizes, int n_in,
                              void* d_out, int out_size, void* d_ws, size_t ws_size,
                              hipStream_t stream)
{
  MegaArgs a;
  a.A_in   = (const float*)d_in[0];
  a.V_in   = (const float*)d_in[1];
  a.L_in   = (const float*)d_in[2];
  a.qmask  = (const float*)d_in[3];
  a.spk    = (const float*)d_in[4];
  a.fc1_W  = (const float*)d_in[5];
  a.fc1_b  = (const float*)d_in[6];
  a.he_w   = (const float*)d_in[7];
  a.ew_w   = (const float*)d_in[8];
  a.attr1  = (const float*)d_in[9];
  a.attr2  = (const float*)d_in[10];
  a.hc_W   = (const float*)d_in[11];
  a.hc_b   = (const float*)d_in[12];
  a.m3_W0  = (const float*)d_in[13];
  a.m3_W1  = (const float*)d_in[14];
  a.m3_Ws  = (const float*)d_in[15];
  a.m3_b   = (const float*)d_in[16];
  a.het    = (const int*)d_in[18];
  a.dout   = (float*)d_out;

  char* ws = (char*)d_ws;
  a.WT   = (ushort_t*)ws;                             // 16 x 512KB bf16 = 8 MB
  a.X1   = (float*)(ws + (size_t)16*MATSZ*2);
  a.OUT  = a.X1  + (size_t)NNODE*512;
  float* H1 = a.OUT + (size_t)NNODE*512;              // slot kept (unused)
  a.HS   = H1   + (size_t)NNODE*512;
  a.G    = a.HS + (size_t)NNODE*512;
  a.EB   = a.G  + (size_t)NNODE*512;                  // NEDGE*512
  a.Gsum = a.EB + (size_t)NEDGE*512;                  // 96*512
  a.Sp   = a.Gsum + 96*512;                           // 96*1024
  a.acc  = a.Sp + 96*1024;
  a.bar  = (unsigned int*)(a.acc + 1);

  init_kernel<<<1,64,0,stream>>>(a.bar, a.acc);
  mega<<<NBLK,256,0,stream>>>(a);

  (void)in_sizes; (void)n_in; (void)out_size; (void)ws_size;
}

// Round 4
// 388.851 us; speedup vs baseline: 3.6396x; 3.6396x over previous
//
#include <hip/hip_runtime.h>

typedef unsigned short ushort_t;
typedef __attribute__((ext_vector_type(4))) float f32x4;
typedef __attribute__((ext_vector_type(8))) short s16x8;
typedef __attribute__((ext_vector_type(8))) unsigned short u16x8;

#define NNODE 2592
#define MATSZ (512*512)
#define INV53 (1.0f/(53.0f + 1e-8f))

__device__ __forceinline__ ushort_t f2b(float f){
  union {unsigned int i; float f;} x; x.f = f;
  unsigned int r = (x.i + 0x7fffu + ((x.i>>16)&1u))>>16;
  return (ushort_t)r;
}

__device__ __forceinline__ void async_copy16(const ushort_t* g, ushort_t* l){
  __builtin_amdgcn_global_load_lds((const __attribute__((address_space(1))) void*)g,
                                   (__attribute__((address_space(3))) void*)l, 16, 0, 0);
}

struct __align__(16) GBuf {
  ushort_t As[2][176*64];   // XOR-swizzled A slab (rows 0..175, 64 k)
  ushort_t Bs[2][128*64];   // XOR-swizzled B tile
};
struct Desc {
  const float* rpA[176];
  const float* rpB[176];
  float rcA[176], rcB[176];
};

// ---------------------------------------------------------------------------
// dgemm core (verified in R3): acc[11][2] = A(desc rows 162+pad)@W[:,col0+128]
// 2-phase pipelined, double-buffered LDS, B via global_load_lds.
// ---------------------------------------------------------------------------
template<bool DUAL>
__device__ __forceinline__ void dgemm_core(GBuf* g, const Desc* ds,
    const ushort_t* W, int col0, f32x4 acc[11][2])
{
  const int tid = threadIdx.x;
  const int wave = tid>>6, lane = tid&63;
  const int ml = lane&15, quad = lane>>4;
  const int lr = lane>>3, lchunk = lane&7;
  const int bswz = (lchunk ^ lr)*8;

  #pragma unroll
  for (int mf=0; mf<11; mf++){
    acc[mf][0] = (f32x4){0.f,0.f,0.f,0.f};
    acc[mf][1] = (f32x4){0.f,0.f,0.f,0.f};
  }
  f32x4 La[6],Lb[6],Lc[6],Ld[6];

  auto loadA = [&](int k0){
    #pragma unroll
    for (int it=0; it<6; it++){
      int c = it*256 + tid;
      if (c < 1408){
        int row = c>>3, k8 = c&7;
        const float* pA = ds->rpA[row] + k0 + k8*8;
        La[it] = *(const f32x4*)pA;
        Lb[it] = *(const f32x4*)(pA+4);
        if (DUAL){
          const float* pB = ds->rpB[row] + k0 + k8*8;
          Lc[it] = *(const f32x4*)pB;
          Ld[it] = *(const f32x4*)(pB+4);
        }
      }
    }
  };
  auto writeA = [&](int buf){
    #pragma unroll
    for (int it=0; it<6; it++){
      int c = it*256 + tid;
      if (c < 1408){
        int row = c>>3, k8 = c&7;
        u16x8 v;
        if (DUAL){
          float cA = ds->rcA[row], cB = ds->rcB[row];
          #pragma unroll
          for (int j=0;j<4;j++){
            v[j]   = f2b(cA*La[it][j] + cB*Lc[it][j]);
            v[4+j] = f2b(cA*Lb[it][j] + cB*Ld[it][j]);
          }
        } else {
          #pragma unroll
          for (int j=0;j<4;j++){
            v[j]   = f2b(La[it][j]);
            v[4+j] = f2b(Lb[it][j]);
          }
        }
        *(u16x8*)&g->As[buf][row*64 + ((k8 ^ (row&7))<<3)] = v;
      }
    }
  };
  auto stageB = [&](int buf, int k0){
    #pragma unroll
    for (int rep=0; rep<4; rep++){
      int bn0 = wave*32 + rep*8;
      const ushort_t* src = W + (size_t)(col0 + bn0 + lr)*512 + k0 + bswz;
      async_copy16(src, &g->Bs[buf][bn0*64]);
    }
  };

  loadA(0); stageB(0,0); writeA(0);
  int cur = 0;
  #pragma unroll
  for (int ks=0; ks<8; ks++){
    __syncthreads();
    if (ks<7){ loadA((ks+1)*64); stageB(cur^1,(ks+1)*64); }
    #pragma unroll
    for (int kh=0; kh<2; kh++){
      const int k8r = kh*4 + quad;
      s16x8 b0, b1;
      {
        int bn = wave*32 + ml;
        b0 = *(const s16x8*)&g->Bs[cur][bn*64 + ((k8r ^ (bn&7))<<3)];
        bn = wave*32 + 16 + ml;
        b1 = *(const s16x8*)&g->Bs[cur][bn*64 + ((k8r ^ (bn&7))<<3)];
      }
      #pragma unroll
      for (int mf=0; mf<11; mf++){
        int ar = mf*16 + ml;
        s16x8 av = *(const s16x8*)&g->As[cur][ar*64 + ((k8r ^ (ar&7))<<3)];
        acc[mf][0] = __builtin_amdgcn_mfma_f32_16x16x32_bf16(av,b0,acc[mf][0],0,0,0);
        acc[mf][1] = __builtin_amdgcn_mfma_f32_16x16x32_bf16(av,b1,acc[mf][1],0,0,0);
      }
    }
    if (ks<7) writeA(cur^1);
    cur ^= 1;
  }
  __syncthreads();   // LDS safe to reuse after this
}

// ---------------------------------------------------------------------------
// prep: 1024 transpose-tile jobs (slots 12..15 = Wself - INV53*W1) +
// 6 attrW GEMV jobs (attr{1,2} @ hc_W[l]) + acc/counter init.
// ---------------------------------------------------------------------------
__global__ __launch_bounds__(256) void prep_kernel(
    const float* __restrict__ fc1, const float* __restrict__ hc,
    const float* __restrict__ m0, const float* __restrict__ m1,
    const float* __restrict__ ms, const float* __restrict__ at1,
    const float* __restrict__ at2, ushort_t* __restrict__ WT,
    float* __restrict__ attrW, float* __restrict__ acc,
    unsigned int* __restrict__ counter)
{
  if (blockIdx.x==0 && threadIdx.x==0){ *acc = 0.f; *counter = 0u; }
  if (blockIdx.x >= 1024){
    int job = blockIdx.x - 1024;     // 0..5
    int l = job>>1, sel = job&1;
    const float* av = sel ? at2 : at1;
    const float* W = hc + (size_t)l*MATSZ;
    int c = threadIdx.x*2;
    float a0=0.f, a1=0.f;
    for (int k=0;k<512;k++){
      float ak = av[k];
      float2 w = *(const float2*)&W[(size_t)k*512 + c];
      a0 += ak*w.x; a1 += ak*w.y;
    }
    attrW[(size_t)(l*2+sel)*512 + c]   = a0;
    attrW[(size_t)(l*2+sel)*512 + c+1] = a1;
    return;
  }
  __shared__ float tile[64][65];
  int w = blockIdx.x>>6, t = blockIdx.x&63, bx = t>>3, by = t&7;
  const float* src = (w==0) ? fc1
                   : (w<4)  ? hc + (size_t)(w-1)*MATSZ
                   : (w<8)  ? m0 + (size_t)(w-4)*MATSZ
                   : (w<12) ? m1 + (size_t)(w-8)*MATSZ
                            : ms + (size_t)(w-12)*MATSZ;
  const float* src2 = (w>=12) ? m1 + (size_t)(w-12)*MATSZ : nullptr;
  ushort_t* dst = WT + (size_t)w*MATSZ;
  int r0 = bx*64, c0 = by*64;
  #pragma unroll
  for (int j=0;j<16;j++){
    int idx = j*256 + threadIdx.x;
    int r = idx>>6, c = idx&63;
    size_t off = (size_t)(r0+r)*512 + c0 + c;
    float v = src[off];
    if (w>=12) v -= INV53 * src2[off];
    tile[r][c] = v;
  }
  __syncthreads();
  #pragma unroll
  for (int j=0;j<16;j++){
    int idx = j*256 + threadIdx.x;
    int r = idx>>6, c = idx&63;
    dst[(size_t)(c0+r)*512 + r0 + c] = f2b(tile[c][r]);
  }
}

// ---------------------------------------------------------------------------
// fc1: X1 = feats @ fc1_W + b, plus Gsum of X1 via quad-shfl.  grid (16,4).
// ---------------------------------------------------------------------------
struct FC1S { GBuf g; Desc ds; unsigned char rowsp[176]; };

__global__ __launch_bounds__(256) void fc1_kernel(
    const float* __restrict__ A_in, const float* __restrict__ V_in,
    const float* __restrict__ L_in, const float* __restrict__ qmask,
    const float* __restrict__ spk, const ushort_t* __restrict__ WT,
    const float* __restrict__ fc1_b, float* __restrict__ X1,
    float* __restrict__ Gsum)
{
  __shared__ FC1S s;
  const int tid = threadIdx.x;
  const int d = blockIdx.x, nc = blockIdx.y;
  if (tid < 176){
    int rc = tid>161 ? 161 : tid;
    int m = rc/54, i = rc-m*54, t = d*54+i;
    const float* base = ((m==0)?L_in:(m==1)?A_in:V_in) + (size_t)t*512;
    int sp = qmask[(i*16+d)*2+1] > qmask[(i*16+d)*2];
    const float* pb = base; float cb = 0.f;
    if (m==0){ pb = spk + sp*512; cb = 1.f; }
    s.ds.rpA[tid]=base; s.ds.rpB[tid]=pb; s.ds.rcA[tid]=1.f; s.ds.rcB[tid]=cb;
    s.rowsp[tid] = (unsigned char)sp;
  }
  __syncthreads();
  f32x4 acc[11][2];
  dgemm_core<true>(&s.g, &s.ds, WT, nc*128, acc);

  const int lane = tid&63, wave = tid>>6;
  const int ml = lane&15, quad = lane>>4;
  #pragma unroll
  for (int nf=0; nf<2; nf++){
    int gcol = nc*128 + wave*32 + nf*16 + ml;
    float bv = fc1_b[gcol];
    float s00=0,s01=0,s10=0,s11=0,s20=0,s21=0;
    #pragma unroll
    for (int mf=0; mf<11; mf++){
      #pragma unroll
      for (int r=0;r<4;r++){
        int row = mf*16 + quad*4 + r;
        if (row < 162){
          float v = acc[mf][nf][r] + bv;
          X1[(size_t)(d*162+row)*512 + gcol] = v;
          bool spb = s.rowsp[row];
          if (row < 54)      { if (spb) s01+=v; else s00+=v; }
          else if (row <108) { if (spb) s11+=v; else s10+=v; }
          else               { if (spb) s21+=v; else s20+=v; }
        }
      }
    }
    #pragma unroll
    for (int off=16; off<64; off<<=1){
      s00 += __shfl_xor(s00, off); s01 += __shfl_xor(s01, off);
      s10 += __shfl_xor(s10, off); s11 += __shfl_xor(s11, off);
      s20 += __shfl_xor(s20, off); s21 += __shfl_xor(s21, off);
    }
    if (quad==0){
      Gsum[(size_t)(d*6+0)*512 + gcol] = s00;
      Gsum[(size_t)(d*6+1)*512 + gcol] = s01;
      Gsum[(size_t)(d*6+2)*512 + gcol] = s10;
      Gsum[(size_t)(d*6+3)*512 + gcol] = s11;
      Gsum[(size_t)(d*6+4)*512 + gcol] = s20;
      Gsum[(size_t)(d*6+5)*512 + gcol] = s21;
    }
  }
}

// ---------------------------------------------------------------------------
// hg: one full hypergraph-conv layer.  Z = src@W (dgemm), then edge-mix on
// the Z side (linear before ReLU): EZ_E = (sum wZ)/de + attr@W, then
// out = relu(rwa*EZ_em + rwb*EZ_eu + b).  grid (16,4).
// ---------------------------------------------------------------------------
struct HGS {
  union {
    GBuf g;
    struct { float Z[162][132]; float EZ[57][128]; } e;
  } u;
  Desc ds;
  float wm[162], wu[162];
  float invde[57];
  float rwa[162], rwb[162];
  int hetl[57];
  unsigned char rowm[162];
};

__global__ __launch_bounds__(256) void hg_kernel(
    const float* __restrict__ src, const float* __restrict__ ew_w,
    const float* __restrict__ he_w, const int* __restrict__ het,
    const float* __restrict__ attrW, const ushort_t* __restrict__ WT,
    const float* __restrict__ hc_b, float* __restrict__ dst, int ll)
{
  __shared__ HGS s;
  const int tid = threadIdx.x;
  const int d = blockIdx.x, nc = blockIdx.y;
  if (tid < 162){ s.wm[tid] = ew_w[d*324+tid]; s.wu[tid] = ew_w[d*324+162+tid]; }
  if (tid < 57) s.hetl[tid] = het[d*57+tid];
  if (tid < 176){
    int rc = tid>161?161:tid;
    s.ds.rpA[tid] = src + (size_t)(d*162+rc)*512;
  }
  __syncthreads();
  if (tid < 54){
    float de = s.wu[tid*3]+s.wu[tid*3+1]+s.wu[tid*3+2];
    s.invde[3+tid] = 1.0f/(de+1e-8f);
  } else if (tid < 57){
    int m = tid-54; float de=0.f;
    for (int i=0;i<54;i++) de += s.wm[m*54+i];
    s.invde[m] = 1.0f/(de+1e-8f);
  }
  if (tid < 162){
    int m = tid/54, i = tid-m*54;
    s.rowm[tid] = (unsigned char)m;
    float w1 = he_w[d*57+m], w2 = he_w[d*57+3+i];
    float invn = 1.0f/(w1+w2+1e-8f);
    s.rwa[tid] = w1*invn; s.rwb[tid] = w2*invn;
  }
  __syncthreads();

  f32x4 acc[11][2];
  dgemm_core<false>(&s.u.g, &s.ds, WT + (size_t)(1+ll)*MATSZ, nc*128, acc);

  const int lane = tid&63, wave = tid>>6;
  const int ml = lane&15, quad = lane>>4;
  // stage Z to LDS (union with gemm buffers, safe after core's final sync)
  #pragma unroll
  for (int nf=0; nf<2; nf++){
    int lc = wave*32 + nf*16 + ml;
    #pragma unroll
    for (int mf=0; mf<11; mf++){
      #pragma unroll
      for (int r=0;r<4;r++){
        int row = mf*16 + quad*4 + r;
        if (row < 162) s.u.e.Z[row][lc] = acc[mf][nf][r];
      }
    }
  }
  __syncthreads();
  {
    int c = tid & 127;
    int gcol = nc*128 + c;
    float aw0 = attrW[(size_t)(ll*2+0)*512 + gcol];   // attr1@W
    float aw1 = attrW[(size_t)(ll*2+1)*512 + gcol];   // attr2@W
    if (tid < 128){
      for (int i=0;i<54;i++){
        float v = s.wu[i*3+0]*s.u.e.Z[i][c]
                + s.wu[i*3+1]*s.u.e.Z[54+i][c]
                + s.wu[i*3+2]*s.u.e.Z[108+i][c];
        float at = s.hetl[3+i] ? aw0 : aw1;
        s.u.e.EZ[3+i][c] = v*s.invde[3+i] + at;
      }
    } else {
      #pragma unroll
      for (int m=0;m<3;m++){
        float v = 0.f;
        for (int i=0;i<54;i++) v += s.wm[m*54+i]*s.u.e.Z[m*54+i][c];
        float at = s.hetl[m] ? aw0 : aw1;
        s.u.e.EZ[m][c] = v*s.invde[m] + at;
      }
    }
  }
  __syncthreads();
  {
    int c = tid & 127, r0 = tid>>7;
    int gcol = nc*128 + c;
    float bv = hc_b[ll*512 + gcol];
    for (int r=r0; r<162; r+=2){
      int m = s.rowm[r], i = r - m*54;
      float v = s.rwa[r]*s.u.e.EZ[m][c] + s.rwb[r]*s.u.e.EZ[3+i][c] + bv;
      dst[(size_t)(d*162+r)*512 + gcol] = fmaxf(v, 0.f);
    }
  }
}

// ---------------------------------------------------------------------------
// rgcn: one full RGCN layer.  Phase0: SpL = GsumIn_d @ {W0|W1} (mini-MFMA,
// verified sp_stage layout).  Main: HS = gin@(Wself-INV53*W1) (dgemm).
// Epilogue: f = relu((S1[sp]+S0[1-sp])*INV53 + HS + b); g = gin + f;
// Gsum-next via quad-shfl.  LAST: dout = OUThg + g, sum(f^2) -> scalar.
// ---------------------------------------------------------------------------
struct RS {
  GBuf g;
  Desc ds;
  float SpL[2][6][128];
  unsigned char rowsp[176];
  unsigned char rowm[176];
  float red[4];
};

template<bool LAST>
__global__ __launch_bounds__(256) void rgcn_kernel(
    const float* __restrict__ gin, const float* __restrict__ GsumIn,
    const float* __restrict__ qmask, const ushort_t* __restrict__ WT,
    const float* __restrict__ m3_b, float* __restrict__ Gout,
    float* __restrict__ GsumOut, const float* __restrict__ OUThg,
    float* __restrict__ dout, float* __restrict__ acc_g,
    unsigned int* __restrict__ counter, int kk)
{
  __shared__ RS s;
  const int tid = threadIdx.x;
  const int d = blockIdx.x, nc = blockIdx.y;
  const int lane = tid&63, wave = tid>>6;
  const int ml = lane&15, quad = lane>>4;

  if (tid < 176){
    int rc = tid>161?161:tid;
    int m = rc/54, i = rc-m*54;
    s.rowm[tid] = (unsigned char)m;
    s.rowsp[tid] = (unsigned char)(qmask[(i*16+d)*2+1] > qmask[(i*16+d)*2]);
    s.ds.rpA[tid] = gin + (size_t)(d*162+rc)*512;
  }
  __syncthreads();

  // phase 0: SpL[mat][row<6][128] = GsumIn_d @ {W0|W1}[:, nc cols]
  {
    const int mat = wave & 1, ch = wave >> 1;
    const ushort_t* Wb = WT + (size_t)(4 + mat*4 + kk)*MATSZ;
    f32x4 sac[4];
    #pragma unroll
    for (int nf=0;nf<4;nf++) sac[nf] = (f32x4){0.f,0.f,0.f,0.f};
    for (int ks=0; ks<16; ks++){
      u16x8 af;
      if (ml < 6){
        const float* gr = GsumIn + (size_t)(d*6+ml)*512 + ks*32 + quad*8;
        f32x4 xa = *(const f32x4*)gr, xb = *(const f32x4*)(gr+4);
        #pragma unroll
        for (int j=0;j<4;j++){ af[j]=f2b(xa[j]); af[4+j]=f2b(xb[j]); }
      } else af = (u16x8){0,0,0,0,0,0,0,0};
      #pragma unroll
      for (int nf=0; nf<4; nf++){
        const ushort_t* wp = Wb + (size_t)(nc*128 + ch*64 + nf*16 + ml)*512 + ks*32 + quad*8;
        s16x8 bf = *(const s16x8*)wp;
        sac[nf] = __builtin_amdgcn_mfma_f32_16x16x32_bf16((s16x8)af, bf, sac[nf],0,0,0);
      }
    }
    #pragma unroll
    for (int nf=0; nf<4; nf++){
      f32x4 v = sac[nf];
      #pragma unroll
      for (int r=0;r<4;r++){
        int row = quad*4+r;
        if (row < 6) s.SpL[mat][row][ch*64 + nf*16 + ml] = v[r];
      }
    }
  }

  f32x4 acc[11][2];
  dgemm_core<false>(&s.g, &s.ds, WT + (size_t)(12+kk)*MATSZ, nc*128, acc);

  float sumsq = 0.f;
  #pragma unroll
  for (int nf=0; nf<2; nf++){
    int lc = wave*32 + nf*16 + ml;
    int gcol = nc*128 + lc;
    float bv = m3_b[kk*512 + gcol];
    float s00=0,s01=0,s10=0,s11=0,s20=0,s21=0;
    #pragma unroll
    for (int mf=0; mf<11; mf++){
      #pragma unroll
      for (int r=0;r<4;r++){
        int row = mf*16 + quad*4 + r;
        if (row < 162){
          int m = s.rowm[row], sp = s.rowsp[row];
          float S1 = s.SpL[1][m*2+sp][lc];
          float S0 = s.SpL[0][m*2+(1-sp)][lc];
          float hs = acc[mf][nf][r] + bv;
          float f = fmaxf((S1+S0)*INV53 + hs, 0.f);
          float gi = s.ds.rpA[row][gcol];
          float gn = gi + f;
          if (LAST){
            sumsq += f*f;
            dout[(size_t)(d*162+row)*512 + gcol] =
                OUThg[(size_t)(d*162+row)*512 + gcol] + gn;
          } else {
            Gout[(size_t)(d*162+row)*512 + gcol] = gn;
            if (row < 54)      { if (sp) s01+=gn; else s00+=gn; }
            else if (row <108) { if (sp) s11+=gn; else s10+=gn; }
            else               { if (sp) s21+=gn; else s20+=gn; }
          }
        }
      }
    }
    if (!LAST){
      #pragma unroll
      for (int off=16; off<64; off<<=1){
        s00 += __shfl_xor(s00, off); s01 += __shfl_xor(s01, off);
        s10 += __shfl_xor(s10, off); s11 += __shfl_xor(s11, off);
        s20 += __shfl_xor(s20, off); s21 += __shfl_xor(s21, off);
      }
      if (quad==0){
        GsumOut[(size_t)(d*6+0)*512 + gcol] = s00;
        GsumOut[(size_t)(d*6+1)*512 + gcol] = s01;
        GsumOut[(size_t)(d*6+2)*512 + gcol] = s10;
        GsumOut[(size_t)(d*6+3)*512 + gcol] = s11;
        GsumOut[(size_t)(d*6+4)*512 + gcol] = s20;
        GsumOut[(size_t)(d*6+5)*512 + gcol] = s21;
      }
    }
  }
  if (LAST){
    #pragma unroll
    for (int off=1; off<64; off<<=1) sumsq += __shfl_xor(sumsq, off);
    if (lane==0) s.red[wave] = sumsq;
    __syncthreads();
    if (tid==0){
      atomicAdd(acc_g, s.red[0]+s.red[1]+s.red[2]+s.red[3]);
      __threadfence();
      unsigned int old = atomicAdd(counter, 1u);
      if (old == 63u)
        dout[(size_t)NNODE*512] = atomicAdd(acc_g, 0.0f) * (1.0f/1327104.0f);
    }
  }
}

// ---------------------------------------------------------------------------
extern "C" void kernel_launch(void* const* d_in, const int* in_sizes, int n_in,
                              void* d_out, int out_size, void* d_ws, size_t ws_size,
                              hipStream_t stream)
{
  const float* A_in   = (const float*)d_in[0];
  const float* V_in   = (const float*)d_in[1];
  const float* L_in   = (const float*)d_in[2];
  const float* qmask  = (const float*)d_in[3];
  const float* spk    = (const float*)d_in[4];
  const float* fc1_W  = (const float*)d_in[5];
  const float* fc1_b  = (const float*)d_in[6];
  const float* he_w   = (const float*)d_in[7];
  const float* ew_w   = (const float*)d_in[8];
  const float* attr1  = (const float*)d_in[9];
  const float* attr2  = (const float*)d_in[10];
  const float* hc_W   = (const float*)d_in[11];
  const float* hc_b   = (const float*)d_in[12];
  const float* m3_W0  = (const float*)d_in[13];
  const float* m3_W1  = (const float*)d_in[14];
  const float* m3_Ws  = (const float*)d_in[15];
  const float* m3_b   = (const float*)d_in[16];
  const int*   het    = (const int*)d_in[18];
  float* dout = (float*)d_out;

  char* ws = (char*)d_ws;
  ushort_t* WT = (ushort_t*)ws;                         // 16 x 512KB bf16 = 8MB
  float* attrW = (float*)(ws + (size_t)16*MATSZ*2);     // [3][2][512]
  float* X1  = attrW + 6*512;
  float* OA  = X1 + (size_t)NNODE*512;
  float* OB  = OA + (size_t)NNODE*512;
  float* GA  = OB + (size_t)NNODE*512;
  float* GB  = GA + (size_t)NNODE*512;
  float* GsA = GB + (size_t)NNODE*512;                  // 96*512
  float* GsB = GsA + 96*512;
  float* acc = GsB + 96*512;
  unsigned int* counter = (unsigned int*)(acc + 1);

  prep_kernel<<<1030,256,0,stream>>>(fc1_W, hc_W, m3_W0, m3_W1, m3_Ws,
                                     attr1, attr2, WT, attrW, acc, counter);
  dim3 grid(16,4);
  fc1_kernel<<<grid,256,0,stream>>>(A_in,V_in,L_in,qmask,spk,WT,fc1_b,X1,GsA);
  hg_kernel<<<grid,256,0,stream>>>(X1, ew_w, he_w, het, attrW, WT, hc_b, OA, 0);
  hg_kernel<<<grid,256,0,stream>>>(OA, ew_w, he_w, het, attrW, WT, hc_b, OB, 1);
  hg_kernel<<<grid,256,0,stream>>>(OB, ew_w, he_w, het, attrW, WT, hc_b, OA, 2);
  rgcn_kernel<false><<<grid,256,0,stream>>>(X1, GsA, qmask, WT, m3_b, GA, GsB,
                                            nullptr, nullptr, acc, counter, 0);
  rgcn_kernel<false><<<grid,256,0,stream>>>(GA, GsB, qmask, WT, m3_b, GB, GsA,
                                            nullptr, nullptr, acc, counter, 1);
  rgcn_kernel<false><<<grid,256,0,stream>>>(GB, GsA, qmask, WT, m3_b, GA, GsB,
                                            nullptr, nullptr, acc, counter, 2);
  rgcn_kernel<true><<<grid,256,0,stream>>>(GA, GsB, qmask, WT, m3_b, nullptr,
                                           nullptr, OA, dout, acc, counter, 3);

  (void)in_sizes; (void)n_in; (void)out_size; (void)ws_size;
}